// Round 11
// baseline (35.665 us; speedup 1.0000x reference)
//
#include <hip/hip_runtime.h>
#include <math.h>

#define N1V    8192
#define N2V    8192
#define BLOCK  1024               // 16 waves
#define NW     16
#define NOCT   16                 // N1 split into 16 chunks across blockIdx.y
#define OCT    (N1V / NOCT)       // 512 points staged per block
#define TILES  (OCT / 16)         // 32 MFMA tiles
#define NPAIR  (TILES / 2)        // 16 tile-pairs (8-point stripes per lane)
#define QPW    32                 // queries per wave = 2 MFMA col-sets
#define QPB    (NW * QPW)         // 512 queries per block
#define SKEYMASK 0xFFFFFFC0u      // stripe key: low 6 bits = stripe id (pair<<2|g)
#define SMASK    0x3Fu
#define PKEYMASK 0xFFFFFE00u      // point key: 14 mantissa bits, low 9 = local idx
#define PMASK    0x1FFu
#define FMAXV  __uint_as_float(0x7F7FFFFFu)

typedef __attribute__((ext_vector_type(8))) short short8;
typedef __attribute__((ext_vector_type(4))) float float4v;

#define INS3(t0,t1,t2,v) do { \
    t2 = __builtin_amdgcn_fmed3f(t1, t2, v); \
    t1 = __builtin_amdgcn_fmed3f(t0, t1, v); \
    t0 = fminf(t0, v); } while (0)

__device__ __forceinline__ void bsplit(float x, unsigned short& h, unsigned short& l) {
    unsigned hb = __float_as_uint(x) & 0xFFFF0000u;
    h = (unsigned short)(hb >> 16);
    float lo = x - __uint_as_float(hb);
    l = (unsigned short)(__float_as_uint(lo) >> 16);
}

// K-slot schedule (A = point rows, B = query cols), d' = |s|^2 - 2 q.s :
//  k0-2: s_h * -2q_h   k3-5: s_l * -2q_h   k6-8: s_h * -2q_l
//  k9: w_h * 1   k10: w_l * 1   k11-31: B zero -> A content irrelevant
__global__ __launch_bounds__(BLOCK, 8)
void knn_part(const float* __restrict__ xyz1,
              const float* __restrict__ xyz2,
              const float* __restrict__ flow1,
              float2* __restrict__ ws)
{
    __shared__ __align__(16) unsigned short sA[TILES * 256]; // 16 KB bf16 A-frags
    __shared__ float4 sPts[OCT];                             // 8 KB exact points

    const int b     = blockIdx.z;
    const int oc    = blockIdx.y;
    const int qbase = blockIdx.x * QPB;
    const int t     = threadIdx.x;
    const int lane  = t & 63;
    const int w     = t >> 6;
    const int col   = lane & 15;
    const int g     = lane >> 4;

    const float* x1 = xyz1 + b * 3 * N1V + oc * OCT;
    const float* f1 = flow1 + b * 3 * N1V + oc * OCT;
    const float* x2 = xyz2 + b * 3 * N2V;

    // ---- stage: exact f32 points + pre-split bf16 A-fragments -------------
    if (t < OCT) {
        const int j = t;
        float sx = x1[j]           + f1[j];
        float sy = x1[N1V + j]     + f1[N1V + j];
        float sz = x1[2*N1V + j]   + f1[2*N1V + j];
        float wv = fmaf(sx, sx, fmaf(sy, sy, sz * sz));
        sPts[j] = make_float4(sx, sy, sz, wv);
        unsigned short xh,xl,yh,yl,zh,zl,wh,wl;
        bsplit(sx, xh, xl); bsplit(sy, yh, yl);
        bsplit(sz, zh, zl); bsplit(wv, wh, wl);
        unsigned base = (unsigned)(j >> 4) * 256u + (unsigned)(j & 15) * 8u;
        *(uint4*)&sA[base] = make_uint4(
            (unsigned)xh | ((unsigned)yh << 16),
            (unsigned)zh | ((unsigned)xl << 16),
            (unsigned)yl | ((unsigned)zl << 16),
            (unsigned)xh | ((unsigned)yh << 16));
        *(uint4*)&sA[base + 128] = make_uint4(
            (unsigned)zh | ((unsigned)wh << 16),
            (unsigned)wl, 0u, 0u);
    }

    // ---- B fragments: 2 query column-sets per wave -------------------------
    short8 bf0, bf1;
    float qxr = 0.f, qyr = 0.f, qzr = 0.f;    // exact query this lane refines
    const int kr = g & 1;                      // col-set this lane refines
    #pragma unroll
    for (int k = 0; k < 2; ++k) {
        int qi = qbase + w * QPW + k * 16 + col;
        float qx = x2[qi], qy = x2[N2V + qi], qz = x2[2*N2V + qi];
        if (k == kr) { qxr = qx; qyr = qy; qzr = qz; }
        unsigned short xh,xl,yh,yl,zh,zl;
        bsplit(-2.0f * qx, xh, xl);
        bsplit(-2.0f * qy, yh, yl);
        bsplit(-2.0f * qz, zh, zl);
        short8 bf = {0,0,0,0,0,0,0,0};
        if (g == 0) {
            bf[0]=(short)xh; bf[1]=(short)yh; bf[2]=(short)zh;
            bf[3]=(short)xh; bf[4]=(short)yh; bf[5]=(short)zh;
            bf[6]=(short)xl; bf[7]=(short)yl;
        } else if (g == 1) {
            bf[0]=(short)zl; bf[1]=(short)0x3F80; bf[2]=(short)0x3F80;  // 1.0
        }
        if (k == 0) bf0 = bf; else bf1 = bf;
    }

    const unsigned short* ap = &sA[(unsigned)((g & 1) * 128 + col * 8)];

    __syncthreads();

    // ---- MFMA scan: 1 ds_read feeds 2 MFMAs; 8-pt stripe tournament --------
    float c00 = FMAXV, c01 = FMAXV, c02 = FMAXV;   // col-set 0
    float c10 = FMAXV, c11 = FMAXV, c12 = FMAXV;   // col-set 1
    const float4v zc = {0.0f, 0.0f, 0.0f, 0.0f};
    #pragma unroll
    for (int pr = 0; pr < NPAIR; ++pr) {
        short8 a0 = *(const short8*)(ap + (2*pr    ) * 256);
        short8 a1 = *(const short8*)(ap + (2*pr + 1) * 256);
        unsigned sid = (unsigned)(pr << 2) | (unsigned)g;
        {   // col-set 0
            float4v pA = __builtin_amdgcn_mfma_f32_16x16x32_bf16(a0, bf0, zc, 0, 0, 0);
            float4v pB = __builtin_amdgcn_mfma_f32_16x16x32_bf16(a1, bf0, zc, 0, 0, 0);
            float m = fminf(fminf(fminf(pA[0], pA[1]), fminf(pA[2], pA[3])),
                            fminf(fminf(pB[0], pB[1]), fminf(pB[2], pB[3])));
            float kf = __uint_as_float((__float_as_uint(m) & SKEYMASK) | sid);
            INS3(c00, c01, c02, kf);
        }
        {   // col-set 1
            float4v pA = __builtin_amdgcn_mfma_f32_16x16x32_bf16(a0, bf1, zc, 0, 0, 0);
            float4v pB = __builtin_amdgcn_mfma_f32_16x16x32_bf16(a1, bf1, zc, 0, 0, 0);
            float m = fminf(fminf(fminf(pA[0], pA[1]), fminf(pA[2], pA[3])),
                            fminf(fminf(pB[0], pB[1]), fminf(pB[2], pB[3])));
            float kf = __uint_as_float((__float_as_uint(m) & SKEYMASK) | sid);
            INS3(c10, c11, c12, kf);
        }
    }

    // ---- butterfly merge of stripe keys across the 4 lane groups -----------
    #pragma unroll
    for (int d = 16; d <= 32; d <<= 1) {
        float r0 = __shfl_xor(c00, d, 64);
        float r1 = __shfl_xor(c01, d, 64);
        float r2 = __shfl_xor(c02, d, 64);
        INS3(c00, c01, c02, r0); INS3(c00, c01, c02, r1); INS3(c00, c01, c02, r2);
        r0 = __shfl_xor(c10, d, 64);
        r1 = __shfl_xor(c11, d, 64);
        r2 = __shfl_xor(c12, d, 64);
        INS3(c10, c11, c12, r0); INS3(c10, c11, c12, r1); INS3(c10, c11, c12, r2);
    }

    // ---- refine col-set kr: 3 stripes x 8 points, exact f32 d2 -------------
    float s0 = kr ? c10 : c00;
    float s1 = kr ? c11 : c01;
    float s2 = kr ? c12 : c02;

    float e0 = FMAXV, e1 = FMAXV, e2 = FMAXV;
    #pragma unroll
    for (int m = 0; m < 3; ++m) {
        float km = (m == 0) ? s0 : (m == 1) ? s1 : s2;
        unsigned sid = __float_as_uint(km) & SMASK;
        int pbase = (int)((sid >> 2) * 32 + (sid & 3) * 4);  // pair*32 + g*4
        #pragma unroll
        for (int h = 0; h < 2; ++h) {
            #pragma unroll
            for (int r = 0; r < 4; ++r) {
                int lidx = pbase + h * 16 + r;
                float4 P = sPts[lidx];
                float dx = P.x - qxr, dy = P.y - qyr, dz = P.z - qzr;
                float d  = fmaf(dx, dx, fmaf(dy, dy, dz * dz));
                float pk = __uint_as_float((__float_as_uint(d) & PKEYMASK)
                                           | (unsigned)lidx);
                INS3(e0, e1, e2, pk);
            }
        }
    }

    // ---- lanes g=0 (col-set 0) and g=1 (col-set 1) write their queries -----
    if (g < 2) {
        const int qir = qbase + w * QPW + kr * 16 + col;
        float2* wq = ws + ((size_t)(b * NOCT + oc) * N2V + qir) * 3;
        wq[0] = make_float2(__uint_as_float(__float_as_uint(e0) & PKEYMASK),
                            __int_as_float(oc * OCT + (int)(__float_as_uint(e0) & PMASK)));
        wq[1] = make_float2(__uint_as_float(__float_as_uint(e1) & PKEYMASK),
                            __int_as_float(oc * OCT + (int)(__float_as_uint(e1) & PMASK)));
        wq[2] = make_float2(__uint_as_float(__float_as_uint(e2) & PKEYMASK),
                            __int_as_float(oc * OCT + (int)(__float_as_uint(e2) & PMASK)));
    }
}

// ---- pass 2: merge 16 chunks, weights, flow gather, output (all CUs) -------
__global__ __launch_bounds__(64)
void knn_merge(const float* __restrict__ xyz2,
               const float* __restrict__ flow1,
               const float2* __restrict__ ws,
               float* __restrict__ out)
{
    const int gid = blockIdx.x * 64 + threadIdx.x;
    const int b   = gid / N2V;
    const int qi  = gid - b * N2V;

    float b0 = FMAXV, b1 = FMAXV, b2 = FMAXV;
    int   j0 = 0, j1 = 0, j2 = 0;
    #pragma unroll 4
    for (int oc = 0; oc < NOCT; ++oc) {
        const float2* wq = ws + ((size_t)(b * NOCT + oc) * N2V + qi) * 3;
        #pragma unroll
        for (int m = 0; m < 3; ++m) {
            float2 c = wq[m];
            float d = c.x;
            int   j = __float_as_int(c.y);
            if (d < b2) {
                if (d < b1) {
                    b2 = b1; j2 = j1;
                    if (d < b0) { b1 = b0; j1 = j0; b0 = d; j0 = j; }
                    else        { b1 = d;  j1 = j; }
                } else { b2 = d; j2 = j; }
            }
        }
    }

    float d0 = fmaxf(sqrtf(fmaxf(b0, 0.0f)), 1e-10f);
    float d1 = fmaxf(sqrtf(fmaxf(b1, 0.0f)), 1e-10f);
    float d2 = fmaxf(sqrtf(fmaxf(b2, 0.0f)), 1e-10f);
    float i0 = 1.0f / d0, i1 = 1.0f / d1, i2 = 1.0f / d2;
    float wsum = i0 + i1 + i2;
    float w0 = i0 / wsum, w1 = i1 / wsum, w2 = i2 / wsum;

    const float* f1 = flow1 + b * 3 * N1V;
    const float* x2 = xyz2 + b * 3 * N2V;
    float fxo = w0 * f1[j0]         + w1 * f1[j1]         + w2 * f1[j2];
    float fyo = w0 * f1[N1V + j0]   + w1 * f1[N1V + j1]   + w2 * f1[N1V + j2];
    float fzo = w0 * f1[2*N1V + j0] + w1 * f1[2*N1V + j1] + w2 * f1[2*N1V + j2];

    float* ob = out + b * 3 * N2V;
    ob[qi]         = x2[qi]         - fxo;
    ob[N2V + qi]   = x2[N2V + qi]   - fyo;
    ob[2*N2V + qi] = x2[2*N2V + qi] - fzo;
}

extern "C" void kernel_launch(void* const* d_in, const int* in_sizes, int n_in,
                              void* d_out, int out_size, void* d_ws, size_t ws_size,
                              hipStream_t stream)
{
    const float* xyz1  = (const float*)d_in[0];
    const float* xyz2  = (const float*)d_in[1];
    const float* flow1 = (const float*)d_in[2];
    float* out = (float*)d_out;
    const int B = in_sizes[0] / (3 * N1V);

    float2* ws = (float2*)d_ws;   // B * NOCT * N2V * 3 * 8 B = 6.3 MB @ B=2

    dim3 grid(N2V / QPB, NOCT, B);    // (16, 16, B) = 512 blocks, 2 per CU
    knn_part<<<grid, BLOCK, 0, stream>>>(xyz1, xyz2, flow1, ws);

    knn_merge<<<(B * N2V) / 64, 64, 0, stream>>>(xyz2, flow1, ws, out);
}